// Round 4
// baseline (11302.027 us; speedup 1.0000x reference)
//
#include <hip/hip_runtime.h>
#include <hip/hip_cooperative_groups.h>

// x: [B=256, T=100, D=4096] f32; Z: [H=1024, D=4096] f32; KFinv: [D, H] f32
// out[:,t,:] = sigmoid((x_t - nb_{t-1}) @ KFinv + b_h) @ Z + b_out), nb_{-1}=b_out
#define T_SEQ 100
#define DD 4096
#define HH 1024
#define BB 256

#define GRID_WG 256   // == CU count: cooperative launch safe at 1 block/CU
#define BLOCK_T 512   // 8 waves

typedef __attribute__((ext_vector_type(8))) short short8;
typedef __attribute__((ext_vector_type(4))) float float4_t;

__device__ __forceinline__ short f2bf(float f) {
  union { float f; unsigned u; } v; v.f = f;
  unsigned r = v.u + 0x7fffu + ((v.u >> 16) & 1u);  // RNE
  return (short)(r >> 16);
}

// one-time prep: f32 [K][N] -> bf16 [N][K]
__global__ __launch_bounds__(256) void transpose_cvt(const float* __restrict__ src,
                                                     short* __restrict__ dst,
                                                     int K, int N) {
  __shared__ float tile[32][33];
  int k0 = blockIdx.x * 32, n0 = blockIdx.y * 32;
  int tx = threadIdx.x & 31, ty = threadIdx.x >> 5;  // 32 x 8
#pragma unroll
  for (int i = 0; i < 32; i += 8)
    tile[ty + i][tx] = src[(size_t)(k0 + ty + i) * N + n0 + tx];
  __syncthreads();
#pragma unroll
  for (int i = 0; i < 32; i += 8)
    dst[(size_t)(n0 + ty + i) * K + k0 + tx] = f2bf(tile[tx][ty + i]);
}

// Barrier-free GEMM main loops: operand fragments stream straight from
// global to VGPRs (16B/lane coalesced, same per-lane addressing the old
// LDS reads used). Cross-wave operand sharing is recovered by L1. The only
// intra-block sync left is the phase-A cross-k reduce (4 KiB LDS).
__global__ __launch_bounds__(BLOCK_T, 1) void gru_persist(
    const float* __restrict__ x, const short* __restrict__ KFt /*[H][D] bf16*/,
    const short* __restrict__ Zt /*[D][H] bf16*/, const float* __restrict__ b_out,
    const float* __restrict__ b_hidden, short* __restrict__ diff /*[B][D] bf16*/,
    short* __restrict__ hb /*[B][H] bf16*/, float* __restrict__ out) {
  __shared__ float red[1024];  // phase-A cross-k reduce buffer (4 KiB)
  auto grid = cooperative_groups::this_grid();

  const int g = blockIdx.x, tid = threadIdx.x;
  const int lane = tid & 63, wid = tid >> 6;
  const int quad = lane >> 4, l15 = lane & 15;
  const int gsize = GRID_WG * BLOCK_T;
  const int gtid = g * BLOCK_T + tid;

  // ---- init: diff_0 = x[:,0,:] - b_out (packed u32 stores)
  for (int idx = gtid; idx < BB * DD / 2; idx += gsize) {
    int m = idx >> 11, d = (idx & 2047) * 2;
    const float* xp = &x[(size_t)m * T_SEQ * DD + d];
    unsigned lo = (unsigned short)f2bf(xp[0] - b_out[d]);
    unsigned hi = (unsigned short)f2bf(xp[1] - b_out[d + 1]);
    ((unsigned*)diff)[idx] = lo | (hi << 16);
  }

  // Phase A mapping: XCD x handles nA slices {4x..4x+3}; 8 m-tiles x 4 n per XCD.
  const int xcd = g & 7, loc = g >> 3;
  const int maA = (loc & 7) * 32;               // m base (tile 32)
  const int naA = (4 * xcd + (loc >> 3)) * 32;  // n base (tile 32)
  const int wkA = wid >> 2, wqA = wid & 3;      // 2 k-halves x 4 quadrant waves
  const int wmA = wqA >> 1, wnA = wqA & 1;
  // Phase B mapping: XCD x handles nB slices {8x..8x+7}; 4 m-tiles x 8 n per XCD.
  const int maB = (loc & 3) * 64;               // m base (tile 64)
  const int naB = (8 * xcd + (loc >> 2)) * 64;  // n base (tile 64)
  const int wmB = wid >> 1, wnB = wid & 1;      // 4 m x 2 n waves over 64x64

  grid.sync();

  for (int t = 0; t < T_SEQ; ++t) {
    // ============ Phase A: hb = diff @ KFinv + b_hidden  (tile 32x32, K=4096)
    {
      const int ar = maA + wmA * 16 + l15;  // diff row
      const int br = naA + wnA * 16 + l15;  // KFt row
      const short* pa = diff + (size_t)ar * DD + wkA * 2048 + quad * 8;
      const short* pb = KFt + (size_t)br * DD + wkA * 2048 + quad * 8;
      float4_t acc = {0.f, 0.f, 0.f, 0.f};
      short8 a0[8], b0[8], a1[8], b1[8];  // double-batched stream (compile-time idx)
#pragma unroll
      for (int j = 0; j < 8; ++j) {
        a0[j] = *(const short8*)(pa + j * 32);
        b0[j] = *(const short8*)(pb + j * 32);
      }
#pragma unroll 1
      for (int kb = 0; kb < 2048; kb += 512) {
#pragma unroll
        for (int j = 0; j < 8; ++j) {
          a1[j] = *(const short8*)(pa + kb + 256 + j * 32);
          b1[j] = *(const short8*)(pb + kb + 256 + j * 32);
        }
#pragma unroll
        for (int j = 0; j < 8; ++j)
          acc = __builtin_amdgcn_mfma_f32_16x16x32_bf16(a0[j], b0[j], acc, 0, 0, 0);
        if (kb + 512 < 2048) {
#pragma unroll
          for (int j = 0; j < 8; ++j) {
            a0[j] = *(const short8*)(pa + kb + 512 + j * 32);
            b0[j] = *(const short8*)(pb + kb + 512 + j * 32);
          }
        }
#pragma unroll
        for (int j = 0; j < 8; ++j)
          acc = __builtin_amdgcn_mfma_f32_16x16x32_bf16(a1[j], b1[j], acc, 0, 0, 0);
      }
      // cross-k-half reduce through LDS, then exclusive-owner bf16 store
      if (wkA == 1) {
#pragma unroll
        for (int r = 0; r < 4; ++r) red[(wqA * 64 + lane) * 4 + r] = acc[r];
      }
      __syncthreads();
      if (wkA == 0) {
#pragma unroll
        for (int r = 0; r < 4; ++r) {
          float v = acc[r] + red[(wqA * 64 + lane) * 4 + r];
          int m = maA + wmA * 16 + quad * 4 + r;
          int n = naA + wnA * 16 + l15;
          float hv = v + b_hidden[n];
          float ov = __shfl_xor(hv, 1);
          if (!(lane & 1)) {
            unsigned w = (unsigned)(unsigned short)f2bf(hv) |
                         ((unsigned)(unsigned short)f2bf(ov) << 16);
            *(unsigned*)&hb[m * HH + n] = w;  // plain store; grid.sync publishes
          }
        }
      }
    }
    grid.sync();

    // ============ Phase B: s = sigmoid(hb @ Z + b_out); out, diff_{t+1} =====
    {
      float4_t acc2[2] = {};
      float xr[8];
      if (t < T_SEQ - 1) {  // hoist x[t+1] loads: latency hides under GEMM
#pragma unroll
        for (int f = 0; f < 2; ++f)
#pragma unroll
          for (int r = 0; r < 4; ++r) {
            int m = maB + wmB * 16 + quad * 4 + r;
            int n = naB + wnB * 32 + f * 16 + l15;
            xr[f * 4 + r] = x[((size_t)m * T_SEQ + t + 1) * DD + n];
          }
      }
      const int am = maB + wmB * 16 + l15;   // hb row
      const int bn = naB + wnB * 32 + l15;   // Zt row (frag 0); frag 1 = +16 rows
      const short* ph = hb + (size_t)am * HH + quad * 8;
      const short* pz0 = Zt + (size_t)bn * HH + quad * 8;
      const short* pz1 = pz0 + (size_t)16 * HH;
      short8 h0[4], u0[4], v0[4], h1[4], u1[4], v1[4];
#pragma unroll
      for (int j = 0; j < 4; ++j) {
        h0[j] = *(const short8*)(ph + j * 32);
        u0[j] = *(const short8*)(pz0 + j * 32);
        v0[j] = *(const short8*)(pz1 + j * 32);
      }
#pragma unroll 1
      for (int kb = 0; kb < 1024; kb += 256) {
#pragma unroll
        for (int j = 0; j < 4; ++j) {
          h1[j] = *(const short8*)(ph + kb + 128 + j * 32);
          u1[j] = *(const short8*)(pz0 + kb + 128 + j * 32);
          v1[j] = *(const short8*)(pz1 + kb + 128 + j * 32);
        }
#pragma unroll
        for (int j = 0; j < 4; ++j) {
          acc2[0] = __builtin_amdgcn_mfma_f32_16x16x32_bf16(h0[j], u0[j], acc2[0], 0, 0, 0);
          acc2[1] = __builtin_amdgcn_mfma_f32_16x16x32_bf16(h0[j], v0[j], acc2[1], 0, 0, 0);
        }
        if (kb + 256 < 1024) {
#pragma unroll
          for (int j = 0; j < 4; ++j) {
            h0[j] = *(const short8*)(ph + kb + 256 + j * 32);
            u0[j] = *(const short8*)(pz0 + kb + 256 + j * 32);
            v0[j] = *(const short8*)(pz1 + kb + 256 + j * 32);
          }
        }
#pragma unroll
        for (int j = 0; j < 4; ++j) {
          acc2[0] = __builtin_amdgcn_mfma_f32_16x16x32_bf16(h1[j], u1[j], acc2[0], 0, 0, 0);
          acc2[1] = __builtin_amdgcn_mfma_f32_16x16x32_bf16(h1[j], v1[j], acc2[1], 0, 0, 0);
        }
      }
#pragma unroll
      for (int f = 0; f < 2; ++f)
#pragma unroll
        for (int r = 0; r < 4; ++r) {
          int m = maB + wmB * 16 + quad * 4 + r;
          int n = naB + wnB * 32 + f * 16 + l15;
          float z = acc2[f][r] + b_out[n];
          float s = 1.f / (1.f + __expf(-z));
          out[((size_t)m * T_SEQ + t) * DD + n] = s;
          if (t < T_SEQ - 1) {
            short db = f2bf(xr[f * 4 + r] - s);
            int ob = __shfl_xor((int)(unsigned short)db, 1);
            if (!(lane & 1)) {
              unsigned w = (unsigned)(unsigned short)db | ((unsigned)ob << 16);
              *(unsigned*)&diff[(size_t)m * DD + n] = w;  // plain store
            }
          }
        }
    }
    grid.sync();
  }
}

extern "C" void kernel_launch(void* const* d_in, const int* in_sizes, int n_in,
                              void* d_out, int out_size, void* d_ws, size_t ws_size,
                              hipStream_t stream) {
  const float* x = (const float*)d_in[0];
  const float* Z = (const float*)d_in[1];
  const float* b_out = (const float*)d_in[2];
  const float* KFinv = (const float*)d_in[3];
  const float* b_hidden = (const float*)d_in[4];
  float* out = (float*)d_out;

  char* ws = (char*)d_ws;
  short* KFt = (short*)ws;                    // [1024][4096] bf16 : 8 MiB
  short* Zt = (short*)(ws + 8388608);         // [4096][1024] bf16 : 8 MiB
  short* diff = (short*)(ws + 16777216);      // [256][4096] bf16  : 2 MiB
  short* hb = (short*)(ws + 18874368);        // [256][1024] bf16  : 512 KiB

  transpose_cvt<<<dim3(128, 32), 256, 0, stream>>>(KFinv, KFt, 4096, 1024);
  transpose_cvt<<<dim3(32, 128), 256, 0, stream>>>(Z, Zt, 1024, 4096);

  void* args[] = {(void*)&x,        (void*)&KFt,  (void*)&Zt, (void*)&b_out,
                  (void*)&b_hidden, (void*)&diff, (void*)&hb, (void*)&out};
  hipLaunchCooperativeKernel((void*)gru_persist, dim3(GRID_WG), dim3(BLOCK_T), args, 0,
                             stream);
}